// Round 4
// baseline (56.144 us; speedup 1.0000x reference)
//
#include <hip/hip_runtime.h>
#include <hip/hip_bf16.h>
#include <math.h>

// Problem:
//   x:   [8,100,100,20] int32 (n_out=80000 outputs, 20 tokens each)
//   emb: [50257,128] f32;  W: [128,1] f32;  b: [1] f32
//   out[o] = dot(gelu(mean_t emb[x[o,t]]), W) + b
constexpr int T_TOK  = 20;
constexpr int DIM    = 128;
constexpr int VOCAB  = 50257;
constexpr int NSLICE = 4;             // slice table = 50257*32*2B = 3.2MB < 4MB L2/XCD
constexpr int SDIM   = DIM / NSLICE;  // 32 dims/slice

typedef unsigned int  uint32x4 __attribute__((ext_vector_type(4)));
typedef int           i32x4    __attribute__((ext_vector_type(4)));
typedef float         f32x4    __attribute__((ext_vector_type(4)));
typedef float         f32x2    __attribute__((ext_vector_type(2)));

// ---- convert: emb f32 -> embt [NSLICE][V][32] bf16 ; x int32 -> ids16 u16 ----
__global__ __launch_bounds__(256) void convert_kernel(
    const float* __restrict__ emb, const int* __restrict__ x,
    ushort* __restrict__ embt, ushort* __restrict__ ids16,
    int nb_emb, int n_ids8)
{
    if ((int)blockIdx.x < nb_emb) {
        const int i = blockIdx.x * 256 + threadIdx.x;
        if (i >= VOCAB * (DIM / 8)) return;
        const int v  = i >> 4;        // vocab row
        const int jc = i & 15;        // 8-dim chunk
        const int s  = jc >> 2;       // slice
        const int jj = jc & 3;        // chunk within slice

        const f32x4* src = reinterpret_cast<const f32x4*>(emb + (size_t)v * DIM + jc * 8);
        const f32x4 a = __builtin_nontemporal_load(src);
        const f32x4 c = __builtin_nontemporal_load(src + 1);

        auto pack2 = [](float lo, float hi) -> unsigned int {
            unsigned int l = __bfloat16_as_ushort(__float2bfloat16(lo));
            unsigned int h = __bfloat16_as_ushort(__float2bfloat16(hi));
            return l | (h << 16);
        };
        uint32x4 u = { pack2(a.x, a.y), pack2(a.z, a.w), pack2(c.x, c.y), pack2(c.z, c.w) };
        ushort* dst = embt + ((size_t)s * VOCAB + v) * SDIM + jj * 8;
        __builtin_nontemporal_store(u, reinterpret_cast<uint32x4*>(dst));
    } else {
        const int i = ((int)blockIdx.x - nb_emb) * 256 + threadIdx.x;  // converts 8 ids
        if (i >= n_ids8) return;
        const i32x4* xp = reinterpret_cast<const i32x4*>(x) + (size_t)i * 2;
        const i32x4 a = __builtin_nontemporal_load(xp);
        const i32x4 c = __builtin_nontemporal_load(xp + 1);
        uint32x4 u = { (unsigned)a.x | ((unsigned)a.y << 16),
                       (unsigned)a.z | ((unsigned)a.w << 16),
                       (unsigned)c.x | ((unsigned)c.y << 16),
                       (unsigned)c.z | ((unsigned)c.w << 16) };
        __builtin_nontemporal_store(u, reinterpret_cast<uint32x4*>(ids16 + (size_t)i * 8));
    }
}

// ---- gather: 4-lane group handles 2 outputs for one slice ----
// block=256 (4 waves) -> 64 groups -> 128 outputs; grid = NSLICE * (n_out/128)
__global__ __launch_bounds__(256) void gather_kernel(
    const ushort* __restrict__ ids16,
    const ushort* __restrict__ embt,
    const float* __restrict__ W,
    float* __restrict__ part,
    int n_out)
{
    const int s     = blockIdx.x & (NSLICE - 1);   // slice; blockIdx%8 RR -> 2 XCDs/slice
    const int obase = ((int)blockIdx.x >> 2) * 128;
    const int g     = threadIdx.x >> 2;            // group 0..63
    const int j     = threadIdx.x & 3;             // lane in group: dims [8j,8j+8)
    const int o0    = obase + g * 2;               // even output; pair = o0, o0+1
    if (o0 >= n_out) return;

    // 40 ids (2 outputs) = 80B, 16B-aligned -> 5 x uint32x4, nontemporal
    unsigned int idw[20];
    {
        const uint32x4* ip = reinterpret_cast<const uint32x4*>(ids16 + (size_t)o0 * T_TOK);
        #pragma unroll
        for (int q = 0; q < 5; ++q) {
            uint32x4 u = __builtin_nontemporal_load(ip + q);
            idw[4 * q + 0] = u.x; idw[4 * q + 1] = u.y;
            idw[4 * q + 2] = u.z; idw[4 * q + 3] = u.w;
        }
    }

    const ushort* base = embt + (size_t)s * VOCAB * SDIM + j * 8;
    f32x2 accA[4] = {{0.f,0.f},{0.f,0.f},{0.f,0.f},{0.f,0.f}};
    f32x2 accB[4] = {{0.f,0.f},{0.f,0.f},{0.f,0.f},{0.f,0.f}};

    #pragma unroll
    for (int t = 0; t < T_TOK; ++t) {
        const unsigned idA = (t & 1) ? (idw[t >> 1] >> 16)        : (idw[t >> 1] & 0xffffu);
        const unsigned idB = (t & 1) ? (idw[10 + (t >> 1)] >> 16) : (idw[10 + (t >> 1)] & 0xffffu);
        const uint32x4 uA = *reinterpret_cast<const uint32x4*>(base + (size_t)idA * SDIM);
        const uint32x4 uB = *reinterpret_cast<const uint32x4*>(base + (size_t)idB * SDIM);
        #pragma unroll
        for (int q = 0; q < 4; ++q) {
            f32x2 vA = { __uint_as_float(uA[q] << 16), __uint_as_float(uA[q] & 0xffff0000u) };
            f32x2 vB = { __uint_as_float(uB[q] << 16), __uint_as_float(uB[q] & 0xffff0000u) };
            accA[q] += vA;                     // v_pk_add_f32
            accB[q] += vB;
        }
    }

    const float inv_t = 1.0f / (float)T_TOK;
    const float kInvSqrt2 = 0.70710678118654752440f;
    const float* wp = W + s * SDIM + j * 8;
    const f32x4 w0 = *reinterpret_cast<const f32x4*>(wp);
    const f32x4 w1 = *reinterpret_cast<const f32x4*>(wp + 4);
    const float wv[8] = { w0.x, w0.y, w0.z, w0.w, w1.x, w1.y, w1.z, w1.w };

    float pA = 0.f, pB = 0.f;
    #pragma unroll
    for (int k = 0; k < 8; ++k) {
        const float aA = accA[k >> 1][k & 1] * inv_t;
        const float aB = accB[k >> 1][k & 1] * inv_t;
        pA += 0.5f * aA * (1.0f + erff(aA * kInvSqrt2)) * wv[k];
        pB += 0.5f * aB * (1.0f + erff(aB * kInvSqrt2)) * wv[k];
    }

    // reduce across the 4-lane group
    pA += __shfl_xor(pA, 1, 64);  pB += __shfl_xor(pB, 1, 64);
    pA += __shfl_xor(pA, 2, 64);  pB += __shfl_xor(pB, 2, 64);

    if (j == 0) __builtin_nontemporal_store(pA, part + (size_t)s * n_out + o0);
    if (j == 1) __builtin_nontemporal_store(pB, part + (size_t)s * n_out + o0 + 1);
}

// ---- reduce: out[o] = b + sum_s part[s][o] ----
__global__ __launch_bounds__(256) void reduce_kernel(const float* __restrict__ part,
                                                     const float* __restrict__ b,
                                                     float* __restrict__ out, int n_out)
{
    const int o = blockIdx.x * 256 + threadIdx.x;
    if (o >= n_out) return;
    float v = b[0];
    #pragma unroll
    for (int s = 0; s < NSLICE; ++s)
        v += __builtin_nontemporal_load(part + (size_t)s * n_out + o);
    out[o] = v;
}

// ---- fallback (round-1 kernel) if ws too small ----
__global__ __launch_bounds__(256) void gelu_embed_fallback(
    const int* __restrict__ x, const float* __restrict__ emb,
    const float* __restrict__ W, const float* __restrict__ b,
    float* __restrict__ out, int n_out)
{
    const int wave = (int)((blockIdx.x * blockDim.x + threadIdx.x) >> 6);
    const int lane = (int)(threadIdx.x & 63);
    if (wave >= n_out) return;
    const int* ids = x + (size_t)wave * T_TOK;
    float2 acc = make_float2(0.f, 0.f);
    #pragma unroll
    for (int t = 0; t < T_TOK; ++t) {
        const int id = ids[t];
        const float2 v = *reinterpret_cast<const float2*>(
            emb + (size_t)id * DIM + (size_t)(lane * 2));
        acc.x += v.x; acc.y += v.y;
    }
    const float inv_t = 1.0f / (float)T_TOK;
    const float ax = acc.x * inv_t, ay = acc.y * inv_t;
    const float kInvSqrt2 = 0.70710678118654752440f;
    const float gx = 0.5f * ax * (1.0f + erff(ax * kInvSqrt2));
    const float gy = 0.5f * ay * (1.0f + erff(ay * kInvSqrt2));
    const float2 w = *reinterpret_cast<const float2*>(W + (size_t)(lane * 2));
    float p = gx * w.x + gy * w.y;
    #pragma unroll
    for (int off = 32; off >= 1; off >>= 1) p += __shfl_down(p, off, 64);
    if (lane == 0) out[wave] = p + b[0];
}

extern "C" void kernel_launch(void* const* d_in, const int* in_sizes, int n_in,
                              void* d_out, int out_size, void* d_ws, size_t ws_size,
                              hipStream_t stream) {
    const int*   x   = (const int*)d_in[0];
    const float* emb = (const float*)d_in[1];
    const float* W   = (const float*)d_in[2];
    const float* b   = (const float*)d_in[3];
    float* out = (float*)d_out;
    const int n_out = out_size;                       // 80000
    const int n_ids = n_out * T_TOK;                  // 1,600,000

    const size_t embt_bytes = (size_t)NSLICE * VOCAB * SDIM * sizeof(ushort); // 12.87 MB
    const size_t ids_bytes  = (size_t)n_ids * sizeof(ushort);                 // 3.2 MB
    const size_t part_bytes = (size_t)NSLICE * n_out * sizeof(float);         // 1.28 MB

    if (ws_size < embt_bytes + ids_bytes + part_bytes) {
        const int blocks = (n_out + 3) / 4;
        gelu_embed_fallback<<<blocks, 256, 0, stream>>>(x, emb, W, b, out, n_out);
        return;
    }

    ushort* embt  = (ushort*)d_ws;
    ushort* ids16 = (ushort*)((char*)d_ws + embt_bytes);
    float*  part  = (float*)((char*)d_ws + embt_bytes + ids_bytes);

    // 1) convert table (bf16, dim-sliced) + ids (u16) in one kernel
    {
        const int nb_emb = (VOCAB * (DIM / 8) + 255) / 256;   // 3142
        const int n_ids8 = n_ids / 8;                         // 200000
        const int nb_ids = (n_ids8 + 255) / 256;              // 782
        convert_kernel<<<nb_emb + nb_ids, 256, 0, stream>>>(emb, x, embt, ids16,
                                                            nb_emb, n_ids8);
    }
    // 2) sliced gather + gelu + partial dot (2 outputs per 4-lane group)
    {
        const int nchunk = (n_out + 127) / 128;               // 625
        gather_kernel<<<NSLICE * nchunk, 256, 0, stream>>>(ids16, embt, W, part, n_out);
    }
    // 3) reduce partials + bias
    {
        const int blocks = (n_out + 255) / 256;
        reduce_kernel<<<blocks, 256, 0, stream>>>(part, b, out, n_out);
    }
}

// Round 5
// 49.662 us; speedup vs baseline: 1.1305x; 1.1305x over previous
//
#include <hip/hip_runtime.h>
#include <hip/hip_bf16.h>
#include <math.h>

// Problem:
//   x:   [8,100,100,20] int32 (n_out=80000 outputs, 20 tokens each)
//   emb: [50257,128] f32;  W: [128,1] f32;  b: [1] f32
//   out[o] = dot(gelu(mean_t emb[x[o,t]]), W) + b
constexpr int T_TOK  = 20;
constexpr int DIM    = 128;
constexpr int VOCAB  = 50257;
constexpr int NSLICE = 4;             // slice table = 50257*32*2B = 3.2MB < 4MB L2/XCD
constexpr int SDIM   = DIM / NSLICE;  // 32 dims/slice

typedef unsigned int  uint32x4 __attribute__((ext_vector_type(4)));
typedef float         f32x2    __attribute__((ext_vector_type(2)));

// ---- convert: emb f32 -> embt [NSLICE][V][32] bf16 ; also out[o] = b ----
__global__ __launch_bounds__(256) void convert_kernel(
    const float* __restrict__ emb, const float* __restrict__ b,
    ushort* __restrict__ embt, float* __restrict__ out,
    int nb_emb, int n_out)
{
    if ((int)blockIdx.x < nb_emb) {
        const int i = blockIdx.x * 256 + threadIdx.x;
        if (i >= VOCAB * (DIM / 8)) return;
        const int v  = i >> 4;        // vocab row
        const int jc = i & 15;        // 8-dim chunk
        const int s  = jc >> 2;       // slice
        const int jj = jc & 3;        // chunk within slice

        const float* src = emb + (size_t)v * DIM + jc * 8;
        const float4 a = *reinterpret_cast<const float4*>(src);
        const float4 c = *reinterpret_cast<const float4*>(src + 4);

        auto pack2 = [](float lo, float hi) -> unsigned int {
            unsigned int l = __bfloat16_as_ushort(__float2bfloat16(lo));
            unsigned int h = __bfloat16_as_ushort(__float2bfloat16(hi));
            return l | (h << 16);
        };
        uint32x4 u = { pack2(a.x, a.y), pack2(a.z, a.w), pack2(c.x, c.y), pack2(c.z, c.w) };
        *reinterpret_cast<uint32x4*>(embt + ((size_t)s * VOCAB + v) * SDIM + jj * 8) = u;
    } else {
        const int i = ((int)blockIdx.x - nb_emb) * 256 + threadIdx.x;
        if (i < n_out) out[i] = b[0];
    }
}

// ---- gather: 8 lanes per (output, slice): 2 token-halves x 4 dim-chunks ----
// block=256 -> 32 outputs per block for one slice; grid = NSLICE * ceil(n_out/32)
__global__ __launch_bounds__(256) void gather_kernel(
    const int* __restrict__ x,
    const ushort* __restrict__ embt,
    const float* __restrict__ W,
    float* __restrict__ out,
    int n_out)
{
    const int s = blockIdx.x & (NSLICE - 1);          // slice; blockIdx%8 RR -> 2 XCDs/slice
    const int o = ((int)blockIdx.x >> 2) * 32 + ((int)threadIdx.x >> 3);
    const int h = ((int)threadIdx.x >> 2) & 1;        // token half: 0 -> t 0..9, 1 -> t 10..19
    const int j = threadIdx.x & 3;                    // dim chunk [8j, 8j+8)
    if (o >= n_out) return;

    // this half's 10 token ids (aligned int4/int4/int2 pieces; order irrelevant)
    const int* xo = x + (size_t)o * T_TOK;
    int ids[10];
    {
        const int4 a = *reinterpret_cast<const int4*>(xo + (h ? 12 : 0));
        const int4 c = *reinterpret_cast<const int4*>(xo + (h ? 16 : 4));
        const int2 e = *reinterpret_cast<const int2*>(xo + (h ? 10 : 8));
        ids[0] = a.x; ids[1] = a.y; ids[2] = a.z; ids[3] = a.w;
        ids[4] = c.x; ids[5] = c.y; ids[6] = c.z; ids[7] = c.w;
        ids[8] = e.x; ids[9] = e.y;
    }

    const ushort* base = embt + (size_t)s * VOCAB * SDIM + j * 8;
    f32x2 acc[4] = {{0.f,0.f},{0.f,0.f},{0.f,0.f},{0.f,0.f}};

    #pragma unroll
    for (int t = 0; t < 10; ++t) {
        const uint32x4 u = *reinterpret_cast<const uint32x4*>(base + (size_t)ids[t] * SDIM);
        #pragma unroll
        for (int q = 0; q < 4; ++q) {
            f32x2 v = { __uint_as_float(u[q] << 16), __uint_as_float(u[q] & 0xffff0000u) };
            acc[q] += v;                              // v_pk_add_f32
        }
    }

    // combine the two token-halves (lanes j <-> j+4)
    float accf[8] = { acc[0].x, acc[0].y, acc[1].x, acc[1].y,
                      acc[2].x, acc[2].y, acc[3].x, acc[3].y };
    #pragma unroll
    for (int k = 0; k < 8; ++k)
        accf[k] += __shfl_xor(accf[k], 4, 64);

    const float inv_t = 1.0f / (float)T_TOK;
    const float kInvSqrt2 = 0.70710678118654752440f;
    const float* wp = W + s * SDIM + j * 8;
    float p = 0.f;
    #pragma unroll
    for (int k = 0; k < 8; ++k) {
        const float a  = accf[k] * inv_t;
        p += 0.5f * a * (1.0f + erff(a * kInvSqrt2)) * wp[k];
    }

    // reduce across the 4 dim-chunk lanes (both halves hold duplicates)
    p += __shfl_xor(p, 1, 64);
    p += __shfl_xor(p, 2, 64);

    if ((threadIdx.x & 7) == 0)
        __hip_atomic_fetch_add(out + o, p, __ATOMIC_RELAXED, __HIP_MEMORY_SCOPE_AGENT);
}

// ---- fallback (round-1 kernel) if ws too small ----
__global__ __launch_bounds__(256) void gelu_embed_fallback(
    const int* __restrict__ x, const float* __restrict__ emb,
    const float* __restrict__ W, const float* __restrict__ b,
    float* __restrict__ out, int n_out)
{
    const int wave = (int)((blockIdx.x * blockDim.x + threadIdx.x) >> 6);
    const int lane = (int)(threadIdx.x & 63);
    if (wave >= n_out) return;
    const int* ids = x + (size_t)wave * T_TOK;
    float2 acc = make_float2(0.f, 0.f);
    #pragma unroll
    for (int t = 0; t < T_TOK; ++t) {
        const int id = ids[t];
        const float2 v = *reinterpret_cast<const float2*>(
            emb + (size_t)id * DIM + (size_t)(lane * 2));
        acc.x += v.x; acc.y += v.y;
    }
    const float inv_t = 1.0f / (float)T_TOK;
    const float ax = acc.x * inv_t, ay = acc.y * inv_t;
    const float kInvSqrt2 = 0.70710678118654752440f;
    const float gx = 0.5f * ax * (1.0f + erff(ax * kInvSqrt2));
    const float gy = 0.5f * ay * (1.0f + erff(ay * kInvSqrt2));
    const float2 w = *reinterpret_cast<const float2*>(W + (size_t)(lane * 2));
    float p = gx * w.x + gy * w.y;
    #pragma unroll
    for (int off = 32; off >= 1; off >>= 1) p += __shfl_down(p, off, 64);
    if (lane == 0) out[wave] = p + b[0];
}

extern "C" void kernel_launch(void* const* d_in, const int* in_sizes, int n_in,
                              void* d_out, int out_size, void* d_ws, size_t ws_size,
                              hipStream_t stream) {
    const int*   x   = (const int*)d_in[0];
    const float* emb = (const float*)d_in[1];
    const float* W   = (const float*)d_in[2];
    const float* b   = (const float*)d_in[3];
    float* out = (float*)d_out;
    const int n_out = out_size;                       // 80000

    const size_t embt_bytes = (size_t)NSLICE * VOCAB * SDIM * sizeof(ushort); // 12.87 MB

    if (ws_size < embt_bytes) {
        const int blocks = (n_out + 3) / 4;
        gelu_embed_fallback<<<blocks, 256, 0, stream>>>(x, emb, W, b, out, n_out);
        return;
    }

    ushort* embt = (ushort*)d_ws;

    // 1) convert table (bf16, dim-sliced) + init out to bias
    {
        const int nb_emb = (VOCAB * (DIM / 8) + 255) / 256;   // 3142
        const int nb_out = (n_out + 255) / 256;               // 313
        convert_kernel<<<nb_emb + nb_out, 256, 0, stream>>>(emb, b, embt, out,
                                                            nb_emb, n_out);
    }
    // 2) sliced gather + gelu + partial dot, atomically accumulated into out
    {
        const int nchunk = (n_out + 31) / 32;                 // 2500
        gather_kernel<<<NSLICE * nchunk, 256, 0, stream>>>(x, embt, W, out, n_out);
    }
}

// Round 6
// 46.102 us; speedup vs baseline: 1.2178x; 1.0772x over previous
//
#include <hip/hip_runtime.h>
#include <hip/hip_bf16.h>
#include <math.h>

// Problem:
//   x:   [8,100,100,20] int32 (n_out=80000 outputs, 20 tokens each)
//   emb: [50257,128] f32;  W: [128,1] f32;  b: [1] f32
//   out[o] = dot(gelu(mean_t emb[x[o,t]]), W) + b
constexpr int T_TOK  = 20;
constexpr int DIM    = 128;
constexpr int VOCAB  = 50257;
constexpr int NSLICE = 4;             // slice table = 50257*32*2B = 3.2MB < 4MB L2/XCD
constexpr int SDIM   = DIM / NSLICE;  // 32 dims/slice

typedef unsigned int  uint32x4 __attribute__((ext_vector_type(4)));
typedef float         f32x2    __attribute__((ext_vector_type(2)));

// Branchless Abramowitz-Stegun 7.1.26 erf, |err| ~1.5e-7 (+ rcp/exp approx ~1e-6).
__device__ __forceinline__ float erf_fast(float z) {
    const float az = fabsf(z);
    const float t  = __builtin_amdgcn_rcpf(fmaf(0.3275911f, az, 1.0f));
    float poly = fmaf(fmaf(fmaf(fmaf(1.061405429f, t, -1.453152027f),
                                t, 1.421413741f),
                           t, -0.284496736f),
                      t, 0.254829592f);
    poly *= t;
    const float e = __expf(-az * az);
    const float r = fmaf(-poly, e, 1.0f);
    return copysignf(r, z);
}

// ---- convert: emb f32 -> embt [NSLICE][V][32] bf16 ; also out[o] = b ----
__global__ __launch_bounds__(256) void convert_kernel(
    const float* __restrict__ emb, const float* __restrict__ b,
    ushort* __restrict__ embt, float* __restrict__ out,
    int nb_emb, int n_out)
{
    if ((int)blockIdx.x < nb_emb) {
        const int i = blockIdx.x * 256 + threadIdx.x;
        if (i >= VOCAB * (DIM / 8)) return;
        const int v  = i >> 4;        // vocab row
        const int jc = i & 15;        // 8-dim chunk
        const int s  = jc >> 2;       // slice
        const int jj = jc & 3;        // chunk within slice

        const float* src = emb + (size_t)v * DIM + jc * 8;
        const float4 a = *reinterpret_cast<const float4*>(src);
        const float4 c = *reinterpret_cast<const float4*>(src + 4);

        auto pack2 = [](float lo, float hi) -> unsigned int {
            unsigned int l = __bfloat16_as_ushort(__float2bfloat16(lo));
            unsigned int h = __bfloat16_as_ushort(__float2bfloat16(hi));
            return l | (h << 16);
        };
        uint32x4 u = { pack2(a.x, a.y), pack2(a.z, a.w), pack2(c.x, c.y), pack2(c.z, c.w) };
        *reinterpret_cast<uint32x4*>(embt + ((size_t)s * VOCAB + v) * SDIM + jj * 8) = u;
    } else {
        const int i = ((int)blockIdx.x - nb_emb) * 256 + threadIdx.x;
        if (i < n_out) out[i] = b[0];
    }
}

// ---- gather: 8 lanes per (output, slice): 2 token-halves x 4 dim-chunks ----
// block=256 -> 32 outputs per block for one slice; grid = NSLICE * ceil(n_out/32)
__global__ __launch_bounds__(256) void gather_kernel(
    const int* __restrict__ x,
    const ushort* __restrict__ embt,
    const float* __restrict__ W,
    float* __restrict__ out,
    int n_out)
{
    const int s = blockIdx.x & (NSLICE - 1);          // slice; blockIdx%8 RR -> 2 XCDs/slice
    const int o = ((int)blockIdx.x >> 2) * 32 + ((int)threadIdx.x >> 3);
    const int h = ((int)threadIdx.x >> 2) & 1;        // token half: 0 -> t 0..9, 1 -> t 10..19
    const int j = threadIdx.x & 3;                    // dim chunk [8j, 8j+8)
    if (o >= n_out) return;

    // this half's 10 token ids (aligned int4/int4/int2 pieces; order irrelevant)
    const int* xo = x + (size_t)o * T_TOK;
    int ids[10];
    {
        const int4 a = *reinterpret_cast<const int4*>(xo + (h ? 12 : 0));
        const int4 c = *reinterpret_cast<const int4*>(xo + (h ? 16 : 4));
        const int2 e = *reinterpret_cast<const int2*>(xo + (h ? 10 : 8));
        ids[0] = a.x; ids[1] = a.y; ids[2] = a.z; ids[3] = a.w;
        ids[4] = c.x; ids[5] = c.y; ids[6] = c.z; ids[7] = c.w;
        ids[8] = e.x; ids[9] = e.y;
    }

    const ushort* base = embt + (size_t)s * VOCAB * SDIM + j * 8;
    f32x2 acc[4] = {{0.f,0.f},{0.f,0.f},{0.f,0.f},{0.f,0.f}};

    #pragma unroll
    for (int t = 0; t < 10; ++t) {
        const uint32x4 u = *reinterpret_cast<const uint32x4*>(base + (size_t)ids[t] * SDIM);
        #pragma unroll
        for (int q = 0; q < 4; ++q) {
            f32x2 v = { __uint_as_float(u[q] << 16), __uint_as_float(u[q] & 0xffff0000u) };
            acc[q] += v;                              // v_pk_add_f32
        }
    }

    // half-combine with dim-split: lane (j,h) ends owning dims j*8 + h*4 + [0,4)
    const float lo[4] = { acc[0].x, acc[0].y, acc[1].x, acc[1].y };
    const float hi[4] = { acc[2].x, acc[2].y, acc[3].x, acc[3].y };
    float sum[4];
    #pragma unroll
    for (int k = 0; k < 4; ++k) {
        const float send = (h == 0) ? hi[k] : lo[k];
        const float recv = __shfl_xor(send, 4, 64);
        const float keep = (h == 0) ? lo[k] : hi[k];
        sum[k] = keep + recv;
    }

    // epilogue: 4 gelu+dot terms per lane (no duplication)
    const float c_z = (1.0f / (float)T_TOK) * 0.70710678118654752440f;
    const float c_h = 0.5f / (float)T_TOK;
    const float* wp = W + s * SDIM + j * 8 + h * 4;
    float p = 0.f;
    #pragma unroll
    for (int k = 0; k < 4; ++k) {
        const float w  = wp[k];
        const float t1 = sum[k] * c_h * w;       // 0.5*a*w
        const float r  = erf_fast(sum[k] * c_z); // erf(a/sqrt2)
        p = fmaf(t1, r, p + t1);                 // += 0.5*a*w*(1+erf)
    }

    // reduce across the 8 lanes of the group (each holds 4 distinct dims)
    p += __shfl_xor(p, 1, 64);
    p += __shfl_xor(p, 2, 64);
    p += __shfl_xor(p, 4, 64);

    if ((threadIdx.x & 7) == 0)
        __hip_atomic_fetch_add(out + o, p, __ATOMIC_RELAXED, __HIP_MEMORY_SCOPE_AGENT);
}

// ---- fallback (round-1 kernel) if ws too small ----
__global__ __launch_bounds__(256) void gelu_embed_fallback(
    const int* __restrict__ x, const float* __restrict__ emb,
    const float* __restrict__ W, const float* __restrict__ b,
    float* __restrict__ out, int n_out)
{
    const int wave = (int)((blockIdx.x * blockDim.x + threadIdx.x) >> 6);
    const int lane = (int)(threadIdx.x & 63);
    if (wave >= n_out) return;
    const int* ids = x + (size_t)wave * T_TOK;
    float2 acc = make_float2(0.f, 0.f);
    #pragma unroll
    for (int t = 0; t < T_TOK; ++t) {
        const int id = ids[t];
        const float2 v = *reinterpret_cast<const float2*>(
            emb + (size_t)id * DIM + (size_t)(lane * 2));
        acc.x += v.x; acc.y += v.y;
    }
    const float inv_t = 1.0f / (float)T_TOK;
    const float ax = acc.x * inv_t, ay = acc.y * inv_t;
    const float kInvSqrt2 = 0.70710678118654752440f;
    const float gx = 0.5f * ax * (1.0f + erff(ax * kInvSqrt2));
    const float gy = 0.5f * ay * (1.0f + erff(ay * kInvSqrt2));
    const float2 w = *reinterpret_cast<const float2*>(W + (size_t)(lane * 2));
    float p = gx * w.x + gy * w.y;
    #pragma unroll
    for (int off = 32; off >= 1; off >>= 1) p += __shfl_down(p, off, 64);
    if (lane == 0) out[wave] = p + b[0];
}

extern "C" void kernel_launch(void* const* d_in, const int* in_sizes, int n_in,
                              void* d_out, int out_size, void* d_ws, size_t ws_size,
                              hipStream_t stream) {
    const int*   x   = (const int*)d_in[0];
    const float* emb = (const float*)d_in[1];
    const float* W   = (const float*)d_in[2];
    const float* b   = (const float*)d_in[3];
    float* out = (float*)d_out;
    const int n_out = out_size;                       // 80000

    const size_t embt_bytes = (size_t)NSLICE * VOCAB * SDIM * sizeof(ushort); // 12.87 MB

    if (ws_size < embt_bytes) {
        const int blocks = (n_out + 3) / 4;
        gelu_embed_fallback<<<blocks, 256, 0, stream>>>(x, emb, W, b, out, n_out);
        return;
    }

    ushort* embt = (ushort*)d_ws;

    // 1) convert table (bf16, dim-sliced) + init out to bias
    {
        const int nb_emb = (VOCAB * (DIM / 8) + 255) / 256;   // 3142
        const int nb_out = (n_out + 255) / 256;               // 313
        convert_kernel<<<nb_emb + nb_out, 256, 0, stream>>>(emb, b, embt, out,
                                                            nb_emb, n_out);
    }
    // 2) sliced gather + gelu + partial dot, atomically accumulated into out
    {
        const int nchunk = (n_out + 31) / 32;                 // 2500
        gather_kernel<<<NSLICE * nchunk, 256, 0, stream>>>(x, embt, W, out, n_out);
    }
}